// Round 1
// baseline (196.040 us; speedup 1.0000x reference)
//
#include <hip/hip_runtime.h>
#include <hip/hip_bf16.h>
#include <stdint.h>

typedef unsigned short u16;
typedef __attribute__((ext_vector_type(8))) short bf16x8;
typedef __attribute__((ext_vector_type(4))) short bf16x4;
typedef __attribute__((ext_vector_type(4))) float f32x4;

typedef __attribute__((address_space(1))) const void gas_t;
typedef __attribute__((address_space(3))) void las_t;

#define DEV __device__ __forceinline__

DEV float bf2f(u16 v){ union{uint32_t u; float f;} x; x.u = ((uint32_t)v)<<16; return x.f; }
DEV u16 f2bf(float f){ union{float f; uint32_t u;} x; x.f=f; uint32_t r = x.u + 0x7fff + ((x.u>>16)&1u); return (u16)(r>>16); }

DEV void gload_lds16(const u16* g, u16* l){
  __builtin_amdgcn_global_load_lds((gas_t*)g, (las_t*)l, 16, 0, 0);
}

// ---------------- fp32 -> bf16 convert ----------------
__global__ void cvt_f32_bf16(const float* __restrict__ src, u16* __restrict__ dst, int n4){
  int i = blockIdx.x*blockDim.x + threadIdx.x;
  if(i < n4){
    float4 v = ((const float4*)src)[i];
    ushort4 o; o.x=f2bf(v.x); o.y=f2bf(v.y); o.z=f2bf(v.z); o.w=f2bf(v.w);
    ((ushort4*)dst)[i] = o;
  }
}

// ---------------- bf16 GEMM: C[M,N] = A[M,K] * B[N,K]^T + bias ----------------
// M=4096 fixed by grid, K=1024 fixed, N passed. 128x128 tile, BK=32, 4 waves.
template<int OUT_F32>
__global__ __launch_bounds__(256,2)
void gemm_bt(const u16* __restrict__ A, const u16* __restrict__ Bw,
             const float* __restrict__ bias, void* __restrict__ Cp, int N)
{
  constexpr int BK = 32, KSTEPS = 1024/BK;
  __shared__ __align__(16) u16 As[128][BK];
  __shared__ __align__(16) u16 Bs[128][BK];
  const int tid = threadIdx.x, w = tid>>6, l = tid&63;
  const int a = l&15, g = l>>4;
  const int m0 = blockIdx.y*128, n0 = blockIdx.x*128;
  const int wr = w>>1, wc = w&1;
  f32x4 zero = {0.f,0.f,0.f,0.f};
  f32x4 acc[4][4];
  #pragma unroll
  for(int m=0;m<4;m++) for(int n=0;n<4;n++) acc[m][n]=zero;

  const int srow = l>>2, scol = (l&3)*8;
  const u16* Ag = A  + (size_t)(m0 + w*32 + srow)*1024 + scol;
  const u16* Bg = Bw + (size_t)(n0 + w*32 + srow)*1024 + scol;

  for(int kt=0; kt<KSTEPS; ++kt){
    if(kt) __syncthreads();
    gload_lds16(Ag + kt*BK,           &As[w*32   ][0]);
    gload_lds16(Ag + kt*BK + 16*1024, &As[w*32+16][0]);
    gload_lds16(Bg + kt*BK,           &Bs[w*32   ][0]);
    gload_lds16(Bg + kt*BK + 16*1024, &Bs[w*32+16][0]);
    __syncthreads();
    bf16x8 af[4], bf[4];
    #pragma unroll
    for(int m=0;m<4;m++) af[m] = *(const bf16x8*)&As[wr*64 + m*16 + a][g*8];
    #pragma unroll
    for(int n=0;n<4;n++) bf[n] = *(const bf16x8*)&Bs[wc*64 + n*16 + a][g*8];
    #pragma unroll
    for(int m=0;m<4;m++)
      #pragma unroll
      for(int n=0;n<4;n++)
        acc[m][n] = __builtin_amdgcn_mfma_f32_16x16x32_bf16(af[m], bf[n], acc[m][n], 0,0,0);
  }
  #pragma unroll
  for(int n=0;n<4;n++){
    int col = n0 + wc*64 + n*16 + a;
    float bv = bias[col];
    #pragma unroll
    for(int m=0;m<4;m++){
      int row = m0 + wr*64 + m*16 + g*4;
      #pragma unroll
      for(int r=0;r<4;r++){
        float v = acc[m][n][r] + bv;
        if(OUT_F32) ((float*)Cp)[(size_t)(row+r)*N + col] = v;
        else        ((u16*)Cp)[(size_t)(row+r)*N + col] = f2bf(v);
      }
    }
  }
}

// ---------------- RoPE + relayout qkv[4096][3072] -> q,k,v [B*H][S][64] ----------------
__global__ void rope_relayout(const u16* __restrict__ qkv, u16* __restrict__ q_r,
                              u16* __restrict__ k_r, u16* __restrict__ v_r)
{
  int t = blockIdx.x*256 + threadIdx.x;   // 262144 threads
  int gI = t&3, h=(t>>2)&15, row=t>>6;
  int s = row & 2047, b = row >> 11;
  int d0 = gI*8;
  const u16* base = qkv + (size_t)row*3072 + h*64 + d0;
  union U { uint4 v; u16 e[8]; };
  U q1,q2,k1,k2,v1,v2, oq1,oq2,ok1,ok2;
  q1.v = *(const uint4*)(base);
  q2.v = *(const uint4*)(base+32);
  k1.v = *(const uint4*)(base+1024);
  k2.v = *(const uint4*)(base+1024+32);
  v1.v = *(const uint4*)(base+2048);
  v2.v = *(const uint4*)(base+2048+32);
  #pragma unroll
  for(int j=0;j<8;j++){
    float d = (float)(d0+j);
    float fr = __expf(-0.28782313662425574f * d);   // 10000^(-d/32)
    float ang = (float)s * fr;
    float sn, cs; sincosf(ang, &sn, &cs);
    float x1 = bf2f(q1.e[j]), x2 = bf2f(q2.e[j]);
    oq1.e[j] = f2bf(x1*cs - x2*sn); oq2.e[j] = f2bf(x1*sn + x2*cs);
    x1 = bf2f(k1.e[j]); x2 = bf2f(k2.e[j]);
    ok1.e[j] = f2bf(x1*cs - x2*sn); ok2.e[j] = f2bf(x1*sn + x2*cs);
  }
  size_t o = ((size_t)(b*16+h)*2048 + s)*64 + d0;
  *(uint4*)(q_r+o) = oq1.v; *(uint4*)(q_r+o+32) = oq2.v;
  *(uint4*)(k_r+o) = ok1.v; *(uint4*)(k_r+o+32) = ok2.v;
  *(uint4*)(v_r+o) = v1.v;  *(uint4*)(v_r+o+32) = v2.v;
}

// ---------------- causal flash attention ----------------
// Q,K,V: [B*H][2048][64] bf16.  O: [4096][1024] bf16 (row = b*2048+s, col = h*64+d)
__global__ __launch_bounds__(256,2)
void attn_fwd(const u16* __restrict__ Q, const u16* __restrict__ K,
              const u16* __restrict__ V, u16* __restrict__ O)
{
  __shared__ __align__(16) u16 Klds[32][72];     // padded: conflict-even
  __shared__ __align__(16) u16 Vtl[64][44];      // V transposed [d][kv]
  __shared__ __align__(16) u16 Plds[4][16][40];  // per-wave P tile [q][kv]
  const int tid=threadIdx.x, w=tid>>6, l=tid&63, a=l&15, g=l>>4;
  const int qb = blockIdx.x & 31, bh = blockIdx.x >> 5;
  const int q0 = qb*64, q0w = q0 + w*16;
  const u16* Qb = Q + ((size_t)bh*2048 + q0w)*64;
  const u16* Kb = K + (size_t)bh*2048*64;
  const u16* Vb = V + (size_t)bh*2048*64;
  bf16x8 qf0 = *(const bf16x8*)(Qb + a*64 + g*8);
  bf16x8 qf1 = *(const bf16x8*)(Qb + a*64 + 32 + g*8);
  f32x4 zero = {0.f,0.f,0.f,0.f};
  f32x4 oacc[4]; for(int i=0;i<4;i++) oacc[i]=zero;
  float m_run=-1e30f, l_run=0.f;
  const int ntiles = (q0>>5) + 2;
  const int kr = tid>>3, kcb = (tid&7)*8;  // K stage map
  const int d4 = tid>>4, kv2 = tid&15;     // V stage map

  for(int t=0;t<ntiles;++t){
    const int kv0 = t*32;
    if(t) __syncthreads();
    // stage K [32][64] -> Klds[32][72]
    uint4 kvv = *(const uint4*)(Kb + (size_t)(kv0+kr)*64 + kcb);
    *(uint4*)&Klds[kr][kcb] = kvv;
    // stage V transposed: pairs over kv, rows = d
    const u16* vs = Vb + (size_t)(kv0 + kv2*2)*64 + d4*4;
    union { uint2 v; u16 e[4]; } va, vc;
    va.v = *(const uint2*)vs;
    vc.v = *(const uint2*)(vs + 64);
    #pragma unroll
    for(int j=0;j<4;j++){
      uint32_t pk = (uint32_t)va.e[j] | ((uint32_t)vc.e[j]<<16);
      *(uint32_t*)&Vtl[d4*4+j][kv2*2] = pk;
    }
    __syncthreads();

    if(kv0 <= q0w + 15){
      // swapped QK^T: S^T[kv][q], q = a (lane-local)
      f32x4 st[2]; st[0]=zero; st[1]=zero;
      #pragma unroll
      for(int h=0;h<2;h++){
        bf16x8 kf0 = *(const bf16x8*)&Klds[h*16 + a][g*8];
        bf16x8 kf1 = *(const bf16x8*)&Klds[h*16 + a][32 + g*8];
        st[h] = __builtin_amdgcn_mfma_f32_16x16x32_bf16(kf0, qf0, st[h],0,0,0);
        st[h] = __builtin_amdgcn_mfma_f32_16x16x32_bf16(kf1, qf1, st[h],0,0,0);
      }
      const int qg = q0w + a;
      float sv[8];
      #pragma unroll
      for(int h=0;h<2;h++)
        #pragma unroll
        for(int r=0;r<4;r++){
          int kvg = kv0 + h*16 + g*4 + r;
          float x = st[h][r]*0.125f;
          sv[h*4+r] = (kvg <= qg) ? x : -1e30f;
        }
      float tmax = sv[0];
      #pragma unroll
      for(int i=1;i<8;i++) tmax=fmaxf(tmax,sv[i]);
      tmax = fmaxf(tmax, __shfl_xor(tmax,16));
      tmax = fmaxf(tmax, __shfl_xor(tmax,32));
      float mnew = fmaxf(m_run, tmax);
      float sc_o = __expf(m_run - mnew);
      m_run = mnew;
      float pv[8]; float psum=0.f;
      #pragma unroll
      for(int i=0;i<8;i++){ pv[i]=__expf(sv[i]-mnew); psum+=pv[i]; }
      psum += __shfl_xor(psum,16);
      psum += __shfl_xor(psum,32);
      l_run = l_run*sc_o + psum;
      float so[4];
      #pragma unroll
      for(int r=0;r<4;r++) so[r] = __shfl(sc_o, g*4+r);
      #pragma unroll
      for(int dc=0;dc<4;dc++){
        f32x4 t2=oacc[dc];
        t2[0]*=so[0]; t2[1]*=so[1]; t2[2]*=so[2]; t2[3]*=so[3];
        oacc[dc]=t2;
      }
      // P -> LDS (bf16), re-fragment for PV
      #pragma unroll
      for(int h=0;h<2;h++){
        uint2 pk;
        pk.x = (uint32_t)f2bf(pv[h*4+0]) | ((uint32_t)f2bf(pv[h*4+1])<<16);
        pk.y = (uint32_t)f2bf(pv[h*4+2]) | ((uint32_t)f2bf(pv[h*4+3])<<16);
        *(uint2*)&Plds[w][a][h*16 + g*4] = pk;
      }
      bf16x8 pf = *(const bf16x8*)&Plds[w][a][g*8];
      #pragma unroll
      for(int dc=0;dc<4;dc++){
        const u16* vp = &Vtl[dc*16 + a][g*8];
        bf16x4 vlo = *(const bf16x4*)vp;
        bf16x4 vhi = *(const bf16x4*)(vp+4);
        bf16x8 vf;
        vf[0]=vlo[0];vf[1]=vlo[1];vf[2]=vlo[2];vf[3]=vlo[3];
        vf[4]=vhi[0];vf[5]=vhi[1];vf[6]=vhi[2];vf[7]=vhi[3];
        oacc[dc] = __builtin_amdgcn_mfma_f32_16x16x32_bf16(pf, vf, oacc[dc],0,0,0);
      }
    }
  }
  float invl[4];
  #pragma unroll
  for(int r=0;r<4;r++){ float lr = __shfl(l_run, g*4+r); invl[r]=1.f/lr; }
  const int b = bh>>4, hh = bh&15;
  #pragma unroll
  for(int dc=0;dc<4;dc++)
    #pragma unroll
    for(int r=0;r<4;r++){
      float v = oacc[dc][r]*invl[r];
      O[((size_t)(b*2048 + q0w + g*4 + r))*1024 + hh*64 + dc*16 + a] = f2bf(v);
    }
}

extern "C" void kernel_launch(void* const* d_in, const int* in_sizes, int n_in,
                              void* d_out, int out_size, void* d_ws, size_t ws_size,
                              hipStream_t stream)
{
  const float* x      = (const float*)d_in[0];
  const float* qkv_w  = (const float*)d_in[1];
  const float* qkv_b  = (const float*)d_in[2];
  const float* proj_w = (const float*)d_in[3];
  const float* proj_b = (const float*)d_in[4];
  float* out = (float*)d_out;
  char* ws = (char*)d_ws;

  u16* xb    = (u16*)(ws);                          // 8 MB  (reused as attn O)
  u16* wqkv  = (u16*)(ws + 8388608);                // 6 MB
  u16* wproj = (u16*)(ws + 8388608 + 6291456);      // 2 MB
  u16* qkvr  = (u16*)(ws + 16777216);               // 24 MB
  u16* q_r   = (u16*)(ws + 41943040);               // 8 MB
  u16* k_r   = q_r + 4194304;                       // 8 MB
  u16* v_r   = k_r + 4194304;                       // 8 MB  (end = 64 MB)
  u16* o_b   = xb;                                  // reuse x-bf16 region

  cvt_f32_bf16<<<4096,256,0,stream>>>(x, xb, 1048576);
  cvt_f32_bf16<<<3072,256,0,stream>>>(qkv_w, wqkv, 786432);
  cvt_f32_bf16<<<1024,256,0,stream>>>(proj_w, wproj, 262144);

  dim3 gA(24,32);
  gemm_bt<0><<<gA,256,0,stream>>>(xb, wqkv, qkv_b, qkvr, 3072);

  rope_relayout<<<1024,256,0,stream>>>(qkvr, q_r, k_r, v_r);

  attn_fwd<<<1024,256,0,stream>>>(q_r, k_r, v_r, o_b);

  dim3 gC(8,32);
  gemm_bt<1><<<gC,256,0,stream>>>(o_b, wproj, proj_b, out, 1024);
}

// Round 2
// 150.208 us; speedup vs baseline: 1.3051x; 1.3051x over previous
//
#include <hip/hip_runtime.h>
#include <hip/hip_bf16.h>
#include <stdint.h>

typedef unsigned short u16;
typedef __attribute__((ext_vector_type(8))) short bf16x8;
typedef __attribute__((ext_vector_type(4))) float f32x4;
typedef __attribute__((ext_vector_type(16))) float f32x16;

typedef __attribute__((address_space(1))) const void gas_t;
typedef __attribute__((address_space(3))) void las_t;

#define DEV __device__ __forceinline__

DEV float bf2f(u16 v){ union{uint32_t u; float f;} x; x.u = ((uint32_t)v)<<16; return x.f; }
DEV u16 f2bf(float f){ union{float f; uint32_t u;} x; x.f=f; uint32_t r = x.u + 0x7fff + ((x.u>>16)&1u); return (u16)(r>>16); }

DEV void gload_lds16(const u16* g, u16* l){
  __builtin_amdgcn_global_load_lds((gas_t*)g, (las_t*)l, 16, 0, 0);
}

// ---------------- fp32 -> bf16 convert ----------------
__global__ void cvt_f32_bf16(const float* __restrict__ src, u16* __restrict__ dst, int n4){
  int i = blockIdx.x*blockDim.x + threadIdx.x;
  if(i < n4){
    float4 v = ((const float4*)src)[i];
    ushort4 o; o.x=f2bf(v.x); o.y=f2bf(v.y); o.z=f2bf(v.z); o.w=f2bf(v.w);
    ((ushort4*)dst)[i] = o;
  }
}

// ---------------- bf16 GEMM: C[M,N] = A[M,K] * B[N,K]^T + bias ----------------
template<int OUT_F32>
__global__ __launch_bounds__(256,2)
void gemm_bt(const u16* __restrict__ A, const u16* __restrict__ Bw,
             const float* __restrict__ bias, void* __restrict__ Cp, int N)
{
  constexpr int BK = 32, KSTEPS = 1024/BK;
  __shared__ __align__(16) u16 As[128][BK];
  __shared__ __align__(16) u16 Bs[128][BK];
  const int tid = threadIdx.x, w = tid>>6, l = tid&63;
  const int a = l&15, g = l>>4;
  const int m0 = blockIdx.y*128, n0 = blockIdx.x*128;
  const int wr = w>>1, wc = w&1;
  f32x4 zero = {0.f,0.f,0.f,0.f};
  f32x4 acc[4][4];
  #pragma unroll
  for(int m=0;m<4;m++) for(int n=0;n<4;n++) acc[m][n]=zero;

  const int srow = l>>2, scol = (l&3)*8;
  const u16* Ag = A  + (size_t)(m0 + w*32 + srow)*1024 + scol;
  const u16* Bg = Bw + (size_t)(n0 + w*32 + srow)*1024 + scol;

  for(int kt=0; kt<KSTEPS; ++kt){
    if(kt) __syncthreads();
    gload_lds16(Ag + kt*BK,           &As[w*32   ][0]);
    gload_lds16(Ag + kt*BK + 16*1024, &As[w*32+16][0]);
    gload_lds16(Bg + kt*BK,           &Bs[w*32   ][0]);
    gload_lds16(Bg + kt*BK + 16*1024, &Bs[w*32+16][0]);
    __syncthreads();
    bf16x8 af[4], bf[4];
    #pragma unroll
    for(int m=0;m<4;m++) af[m] = *(const bf16x8*)&As[wr*64 + m*16 + a][g*8];
    #pragma unroll
    for(int n=0;n<4;n++) bf[n] = *(const bf16x8*)&Bs[wc*64 + n*16 + a][g*8];
    #pragma unroll
    for(int m=0;m<4;m++)
      #pragma unroll
      for(int n=0;n<4;n++)
        acc[m][n] = __builtin_amdgcn_mfma_f32_16x16x32_bf16(af[m], bf[n], acc[m][n], 0,0,0);
  }
  #pragma unroll
  for(int n=0;n<4;n++){
    int col = n0 + wc*64 + n*16 + a;
    float bv = bias[col];
    #pragma unroll
    for(int m=0;m<4;m++){
      int row = m0 + wr*64 + m*16 + g*4;
      #pragma unroll
      for(int r=0;r<4;r++){
        float v = acc[m][n][r] + bv;
        if(OUT_F32) ((float*)Cp)[(size_t)(row+r)*N + col] = v;
        else        ((u16*)Cp)[(size_t)(row+r)*N + col] = f2bf(v);
      }
    }
  }
}

// ---------------- RoPE + relayout qkv[4096][3072] -> q,k,v [B*H][S][64] ----------------
__global__ void rope_relayout(const u16* __restrict__ qkv, u16* __restrict__ q_r,
                              u16* __restrict__ k_r, u16* __restrict__ v_r)
{
  int t = blockIdx.x*256 + threadIdx.x;
  int gI = t&3, h=(t>>2)&15, row=t>>6;
  int s = row & 2047, b = row >> 11;
  int d0 = gI*8;
  const u16* base = qkv + (size_t)row*3072 + h*64 + d0;
  union U { uint4 v; u16 e[8]; };
  U q1,q2,k1,k2,v1,v2, oq1,oq2,ok1,ok2;
  q1.v = *(const uint4*)(base);
  q2.v = *(const uint4*)(base+32);
  k1.v = *(const uint4*)(base+1024);
  k2.v = *(const uint4*)(base+1024+32);
  v1.v = *(const uint4*)(base+2048);
  v2.v = *(const uint4*)(base+2048+32);
  #pragma unroll
  for(int j=0;j<8;j++){
    float d = (float)(d0+j);
    float fr = __expf(-0.28782313662425574f * d);
    float ang = (float)s * fr;
    float sn, cs; sincosf(ang, &sn, &cs);
    float x1 = bf2f(q1.e[j]), x2 = bf2f(q2.e[j]);
    oq1.e[j] = f2bf(x1*cs - x2*sn); oq2.e[j] = f2bf(x1*sn + x2*cs);
    x1 = bf2f(k1.e[j]); x2 = bf2f(k2.e[j]);
    ok1.e[j] = f2bf(x1*cs - x2*sn); ok2.e[j] = f2bf(x1*sn + x2*cs);
  }
  size_t o = ((size_t)(b*16+h)*2048 + s)*64 + d0;
  *(uint4*)(q_r+o) = oq1.v; *(uint4*)(q_r+o+32) = oq2.v;
  *(uint4*)(k_r+o) = ok1.v; *(uint4*)(k_r+o+32) = ok2.v;
  *(uint4*)(v_r+o) = v1.v;  *(uint4*)(v_r+o+32) = v2.v;
}

// ---------------- wave-autonomous causal flash attention ----------------
// Q,K,V: [B*H][2048][64] bf16.  O: [4096][1024] bf16.
// One wave owns 32 q-rows. Swapped QK^T and swapped PV (32x32x16 MFMA),
// q is lane-local (col = lane&31) throughout -> softmax state is per-lane.
// No LDS, no barriers; cross-half exchange via shfl_xor(32).
__global__ __launch_bounds__(256,2)
void attn_fwd2(const u16* __restrict__ Q, const u16* __restrict__ K,
               const u16* __restrict__ V, u16* __restrict__ O)
{
  const int tid = threadIdx.x, w = tid>>6, l = tid&63;
  const int lo = l&31, hi = l>>5;
  const int b0 = blockIdx.x;                 // 512 blocks
  const int wg = (b0&7)*64 + (b0>>3);        // XCD-chunked swizzle (bijective, 512%8==0)
  const int bh = wg>>4, g = wg&15;
  const int j = w*16 + g;                    // q-tile 0..63 (per-wave, balanced)
  const int q0 = j*32;

  const u16* Qb = Q + ((size_t)bh*2048 + q0)*64;
  const u16* Kb = K + (size_t)bh*2048*64;
  const u16* Vb = V + (size_t)bh*2048*64;

  bf16x8 qf[4];                              // Q[q=lo][16s + hi*8 .. +8]
  #pragma unroll
  for(int s=0;s<4;s++) qf[s] = *(const bf16x8*)(Qb + lo*64 + s*16 + hi*8);

  const u16* kl = Kb + lo*64 + hi*8;         // + kv0*64 + s*16
  const u16* vl = Vb + (size_t)(hi*8)*64 + lo; // + kv0*64 + (16*s2+i)*64 + dt*32

  f32x16 oacc0, oacc1;
  #pragma unroll
  for(int r=0;r<16;r++){ oacc0[r]=0.f; oacc1[r]=0.f; }
  float m_run = -1e30f, l_run = 0.f;

  for(int t=0; t<=j; ++t){
    const int kv0 = t*32;
    const u16* kt = kl + (size_t)kv0*64;
    const u16* vt = vl + (size_t)kv0*64;

    bf16x8 kf[4];
    #pragma unroll
    for(int s=0;s<4;s++) kf[s] = *(const bf16x8*)(kt + s*16);

    // V^T fragments: vu[dt*2+s2].e[i] = V[kv0+16*s2+hi*8+i][dt*32+lo]
    union VU { bf16x8 v; u16 e[8]; } vu[4];
    #pragma unroll
    for(int dt=0;dt<2;dt++)
      #pragma unroll
      for(int s2=0;s2<2;s2++)
        #pragma unroll
        for(int i2=0;i2<8;i2++)
          vu[dt*2+s2].e[i2] = vt[(16*s2+i2)*64 + dt*32];

    // S^T[kv][q]: col=q=lo, row kv_l=(r&3)+8*(r>>2)+4*hi
    f32x16 st;
    #pragma unroll
    for(int r=0;r<16;r++) st[r]=0.f;
    #pragma unroll
    for(int s=0;s<4;s++)
      st = __builtin_amdgcn_mfma_f32_32x32x16_bf16(kf[s], qf[s], st, 0,0,0);

    float sv[16];
    #pragma unroll
    for(int r=0;r<16;r++) sv[r] = st[r]*0.125f;
    if(t==j){
      #pragma unroll
      for(int r=0;r<16;r++){
        const int kvl = (r&3)+8*(r>>2);
        sv[r] = (kvl + 4*hi <= lo) ? sv[r] : -1e30f;
      }
    }

    float mx[8];
    #pragma unroll
    for(int i=0;i<8;i++) mx[i] = fmaxf(sv[i], sv[i+8]);
    #pragma unroll
    for(int s=4;s>=1;s>>=1)
      #pragma unroll
      for(int i=0;i<s;i++) mx[i] = fmaxf(mx[i], mx[i+s]);
    float pmax = fmaxf(mx[0], __shfl_xor(mx[0], 32));

    // defer-max (T13): skip rescale when max grew by <= 8
    if(!__all(pmax <= m_run + 8.f)){
      float mnew = fmaxf(m_run, pmax);
      float corr = __expf(m_run - mnew);
      l_run *= corr;
      #pragma unroll
      for(int r=0;r<16;r++){ oacc0[r]*=corr; oacc1[r]*=corr; }
      m_run = mnew;
    }

    float p[16];
    #pragma unroll
    for(int r=0;r<16;r++) p[r] = __expf(sv[r] - m_run);
    float sm[8];
    #pragma unroll
    for(int i=0;i<8;i++) sm[i] = p[i] + p[i+8];
    #pragma unroll
    for(int s=4;s>=1;s>>=1)
      #pragma unroll
      for(int i=0;i<s;i++) sm[i] += sm[i+s];
    l_run += sm[0] + __shfl_xor(sm[0], 32);

    // P -> bf16 fragments, cross-half exchange
    uint32_t pk[8], rpk[8];
    #pragma unroll
    for(int i=0;i<8;i++) pk[i] = (uint32_t)f2bf(p[2*i]) | ((uint32_t)f2bf(p[2*i+1])<<16);
    #pragma unroll
    for(int i=0;i<8;i++) rpk[i] = (uint32_t)__shfl_xor((int)pk[i], 32);

    union PF { bf16x8 v; uint32_t u[4]; } pf0, pf1;
    pf0.u[0] = hi ? rpk[2] : pk[0];
    pf0.u[1] = hi ? rpk[3] : pk[1];
    pf0.u[2] = hi ? pk[2]  : rpk[0];
    pf0.u[3] = hi ? pk[3]  : rpk[1];
    pf1.u[0] = hi ? rpk[6] : pk[4];
    pf1.u[1] = hi ? rpk[7] : pk[5];
    pf1.u[2] = hi ? pk[6]  : rpk[4];
    pf1.u[3] = hi ? pk[7]  : rpk[5];

    // O^T[d][q] += V^T[d][kv] * P[q][kv]
    oacc0 = __builtin_amdgcn_mfma_f32_32x32x16_bf16(vu[0].v, pf0.v, oacc0, 0,0,0);
    oacc0 = __builtin_amdgcn_mfma_f32_32x32x16_bf16(vu[1].v, pf1.v, oacc0, 0,0,0);
    oacc1 = __builtin_amdgcn_mfma_f32_32x32x16_bf16(vu[2].v, pf0.v, oacc1, 0,0,0);
    oacc1 = __builtin_amdgcn_mfma_f32_32x32x16_bf16(vu[3].v, pf1.v, oacc1, 0,0,0);
  }

  const float invl = 1.f / l_run;
  const int row_g = (bh>>4)*2048 + q0 + lo;
  u16* Ob = O + (size_t)row_g*1024 + (bh&15)*64;
  #pragma unroll
  for(int g2=0; g2<4; g2++){
    uint2 pr;
    pr.x = (uint32_t)f2bf(oacc0[4*g2+0]*invl) | ((uint32_t)f2bf(oacc0[4*g2+1]*invl)<<16);
    pr.y = (uint32_t)f2bf(oacc0[4*g2+2]*invl) | ((uint32_t)f2bf(oacc0[4*g2+3]*invl)<<16);
    *(uint2*)(Ob + 8*g2 + 4*hi) = pr;
  }
  #pragma unroll
  for(int g2=0; g2<4; g2++){
    uint2 pr;
    pr.x = (uint32_t)f2bf(oacc1[4*g2+0]*invl) | ((uint32_t)f2bf(oacc1[4*g2+1]*invl)<<16);
    pr.y = (uint32_t)f2bf(oacc1[4*g2+2]*invl) | ((uint32_t)f2bf(oacc1[4*g2+3]*invl)<<16);
    *(uint2*)(Ob + 32 + 8*g2 + 4*hi) = pr;
  }
}

extern "C" void kernel_launch(void* const* d_in, const int* in_sizes, int n_in,
                              void* d_out, int out_size, void* d_ws, size_t ws_size,
                              hipStream_t stream)
{
  const float* x      = (const float*)d_in[0];
  const float* qkv_w  = (const float*)d_in[1];
  const float* qkv_b  = (const float*)d_in[2];
  const float* proj_w = (const float*)d_in[3];
  const float* proj_b = (const float*)d_in[4];
  float* out = (float*)d_out;
  char* ws = (char*)d_ws;

  u16* xb    = (u16*)(ws);
  u16* wqkv  = (u16*)(ws + 8388608);
  u16* wproj = (u16*)(ws + 8388608 + 6291456);
  u16* qkvr  = (u16*)(ws + 16777216);
  u16* q_r   = (u16*)(ws + 41943040);
  u16* k_r   = q_r + 4194304;
  u16* v_r   = k_r + 4194304;
  u16* o_b   = xb;

  cvt_f32_bf16<<<4096,256,0,stream>>>(x, xb, 1048576);
  cvt_f32_bf16<<<3072,256,0,stream>>>(qkv_w, wqkv, 786432);
  cvt_f32_bf16<<<1024,256,0,stream>>>(proj_w, wproj, 262144);

  dim3 gA(24,32);
  gemm_bt<0><<<gA,256,0,stream>>>(xb, wqkv, qkv_b, qkvr, 3072);

  rope_relayout<<<1024,256,0,stream>>>(qkvr, q_r, k_r, v_r);

  attn_fwd2<<<512,256,0,stream>>>(q_r, k_r, v_r, o_b);

  dim3 gC(8,32);
  gemm_bt<1><<<gC,256,0,stream>>>(o_b, wproj, proj_b, out, 1024);
}